// Round 4
// baseline (722.561 us; speedup 1.0000x reference)
//
#include <hip/hip_runtime.h>
#include <hip/hip_bf16.h>
#include <cmath>

typedef __bf16 bf16_t;
typedef bf16_t bf16x8 __attribute__((ext_vector_type(8)));
typedef float f32x4 __attribute__((ext_vector_type(4)));

__device__ __forceinline__ f32x4 zero4(){ f32x4 z; z[0]=0.f; z[1]=0.f; z[2]=0.f; z[3]=0.f; return z; }

__device__ __forceinline__ bf16x8 cvt8(float4 a, float4 b){
  bf16x8 r;
  r[0]=(bf16_t)a.x; r[1]=(bf16_t)a.y; r[2]=(bf16_t)a.z; r[3]=(bf16_t)a.w;
  r[4]=(bf16_t)b.x; r[5]=(bf16_t)b.y; r[6]=(bf16_t)b.z; r[7]=(bf16_t)b.w;
  return r;
}

__device__ __forceinline__ float gelu_tanh_f(float x){
  float x3 = x*x*x;
  return 0.5f*x*(1.0f + tanhf(0.7978845608028654f*(x + 0.044715f*x3)));
}

// chunk swizzle for bf16 A-operands: 16B chunk (col>>3)&3 XOR'd by (row>>1)&3
__device__ __forceinline__ int swz_col(int row, int col){
  return (col & ~31) | (((((col>>3)&3) ^ ((row>>1)&3)))<<3) | (col&7);
}

#if defined(__has_builtin)
#if __has_builtin(__builtin_amdgcn_global_load_lds)
#define HAS_GLDS 1
#endif
#endif

__device__ __forceinline__ void async_cp16(const bf16_t* g, bf16_t* l){
#ifdef HAS_GLDS
  __builtin_amdgcn_global_load_lds(
      (const __attribute__((address_space(1))) unsigned int*)g,
      (__attribute__((address_space(3))) unsigned int*)l, 16, 0, 0);
#else
  *(bf16x8*)(l + (threadIdx.x & 63)*8) = *(const bf16x8*)g;
#endif
}

// ============ GEMM tile body: C[128,64] block of C[512,N] = A_bf16swz[512,K] * W_f32[N,K]^T ============
// EPI bits: 1 = store fp32 linear, 2 = store bf16 linear, 4 = store bf16 swizzled, 8 = gelu
template<int EPI>
__device__ __forceinline__ void gemm128_body(
    const bf16_t* __restrict__ A, const float* __restrict__ Wt,
    const float* __restrict__ biast,
    float* __restrict__ Cf, bf16_t* __restrict__ Cb,
    int Nc, int K, int kt0, int ktn, int brow, int ccol0)
{
  __shared__ __align__(16) bf16_t As[2][128*32];   // linear rows of 64B
  __shared__ __align__(16) bf16_t Bs[2][64*40];    // padded rows of 80B

  const int tid  = threadIdx.x;
  const int lane = tid & 63;
  const int wave = tid >> 6;
  const int wr = wave >> 1, wc = wave & 1;

  auto stageA = [&](int buf, int kt){
    const bf16_t* s = A + (size_t)(brow + (tid>>2))*K + kt*32 + (tid&3)*8;
#ifdef HAS_GLDS
    bf16_t* base = &As[buf][wave*512];
    async_cp16(s,               base);
    async_cp16(s + (size_t)64*K, base + 2048);
#else
    *(bf16x8*)&As[buf][tid*8]        = *(const bf16x8*)s;
    *(bf16x8*)&As[buf][2048 + tid*8] = *(const bf16x8*)(s + (size_t)64*K);
#endif
  };

  float4 gb0, gb1;
  auto loadB = [&](int kt){
    const float* p = Wt + (size_t)(tid>>2)*K + kt*32 + (tid&3)*8;
    gb0 = *(const float4*)p; gb1 = *(const float4*)(p+4);
  };
  auto writeB = [&](int buf){
    *(bf16x8*)&Bs[buf][(tid>>2)*40 + (tid&3)*8] = cvt8(gb0, gb1);
  };

  f32x4 acc[4][2];
  #pragma unroll
  for (int m=0;m<4;m++){ acc[m][0]=zero4(); acc[m][1]=zero4(); }

  stageA(0, kt0);
  loadB(kt0);
  writeB(0);
  __syncthreads();

  for (int t=0; t<ktn; ++t){
    const int cur = t & 1;
    if (t+1 < ktn){ stageA(cur^1, kt0+t+1); loadB(kt0+t+1); }
    bf16x8 af[4], bfr[2];
    #pragma unroll
    for (int m=0;m<4;m++){
      const int R = wr*64 + m*16 + (lane&15);
      const int c = (lane>>4) ^ ((R>>1)&3);
      af[m] = *(const bf16x8*)&As[cur][R*32 + c*8];
    }
    #pragma unroll
    for (int n=0;n<2;n++)
      bfr[n] = *(const bf16x8*)&Bs[cur][(wc*32 + n*16 + (lane&15))*40 + (lane>>4)*8];
    #pragma unroll
    for (int m=0;m<4;m++)
      #pragma unroll
      for (int n=0;n<2;n++)
        acc[m][n] = __builtin_amdgcn_mfma_f32_16x16x32_bf16(af[m], bfr[n], acc[m][n], 0,0,0);
    if (t+1 < ktn) writeB(cur^1);
    __syncthreads();
  }

  #pragma unroll
  for (int m=0;m<4;m++){
    #pragma unroll
    for (int n=0;n<2;n++){
      const int col = wc*32 + n*16 + (lane&15);
      const float bv = biast ? biast[col] : 0.f;
      #pragma unroll
      for (int r=0;r<4;r++){
        const int gm = brow + wr*64 + m*16 + (lane>>4)*4 + r;
        float v = acc[m][n][r] + bv;
        if (EPI & 8) v = gelu_tanh_f(v);
        if (EPI & 1) Cf[(size_t)gm*Nc + ccol0 + col] = v;
        if (EPI & 2) Cb[(size_t)gm*Nc + ccol0 + col] = (bf16_t)v;
        if (EPI & 4) Cb[(size_t)gm*Nc + swz_col(gm, ccol0 + col)] = (bf16_t)v;
      }
    }
  }
}

// XCD-aware decode: xcd = lin&7 (HW round-robin); m_tile = (lin>>1)&3 so each
// XCD pair serves ONE 128-row A-block (1 MB, L2-resident); n/z walk contiguously.
template<int EPI>
__global__ __launch_bounds__(256,3) void gemm128_kernel(
    const bf16_t* __restrict__ A, const float* __restrict__ W,
    const float* __restrict__ bias,
    float* __restrict__ Cf, bf16_t* __restrict__ Cb, int N, int K, int nt)
{
  const int lin = blockIdx.x;
  const int m = (lin>>1)&3;
  const int o = ((lin>>3)<<1) | (lin&1);
  const int n_tile = o % nt;
  const int z = o / nt;
  const int kz = (gridDim.x >> 2) / nt;
  const int ktn = (K>>5) / kz;
  gemm128_body<EPI>(A, W + (size_t)(n_tile*64)*K,
                    bias ? bias + n_tile*64 : nullptr,
                    (EPI&1) ? Cf + (size_t)z*512*N : nullptr, Cb,
                    N, K, z*ktn, ktn, m*128, n_tile*64);
}

__global__ __launch_bounds__(256,3) void gemm128_qkv_kernel(
    const bf16_t* __restrict__ A,
    const float* __restrict__ W0, const float* __restrict__ W1, const float* __restrict__ W2,
    const float* __restrict__ b0, const float* __restrict__ b1, const float* __restrict__ b2,
    bf16_t* __restrict__ C0, bf16_t* __restrict__ C1, bf16_t* __restrict__ C2)
{
  const int lin = blockIdx.x;
  const int m = (lin>>1)&3;
  const int o = ((lin>>3)<<1) | (lin&1);   // [0,192)
  const int which = o >> 6;
  const int lc = (o & 63) * 64;
  const float* W    = (which==0) ? W0 : ((which==1) ? W1 : W2);
  const float* bias = (which==0) ? b0 : ((which==1) ? b1 : b2);
  bf16_t* C         = (which==0) ? C0 : ((which==1) ? C1 : C2);
  gemm128_body<2>(A, W + (size_t)lc*4096, bias + lc, nullptr, C,
                  4096, 4096, 0, 128, m*128, lc);
}

// ============ flash attention: grid (8 qblocks, 64 heads), 256 thr, 16 q-rows/wave ============
__global__ void attn_kernel(
    const bf16_t* __restrict__ q, const bf16_t* __restrict__ k,
    const bf16_t* __restrict__ v, bf16_t* __restrict__ ctx)
{
  constexpr int HID = 4096;
  const int qblk = blockIdx.x, head = blockIdx.y;
  const int tid = threadIdx.x, lane = tid & 63, wave = tid >> 6;

  __shared__ __align__(16) bf16_t Ks[128][72];
  __shared__ __align__(16) bf16_t Vt[64][136];
  __shared__ __align__(16) bf16_t Ps[4][16][136];

  bf16x8 qf[2];
  const int qrow0 = qblk*64 + wave*16;
  #pragma unroll
  for (int ks=0;ks<2;ks++)
    qf[ks] = *(const bf16x8*)(q + (size_t)(qrow0 + (lane&15))*HID + head*64 + ks*32 + (lane>>4)*8);

  f32x4 o[4];
  float mrow[4], lrow[4];
  #pragma unroll
  for (int n=0;n<4;n++) o[n] = zero4();
  #pragma unroll
  for (int r=0;r<4;r++){ mrow[r] = -1e30f; lrow[r] = 0.f; }

  for (int t=0; t<4; ++t){
    __syncthreads();
    #pragma unroll
    for (int i=0;i<4;i++){
      int s = tid + i*256; int row = s>>3; int c0 = (s&7)*8;
      *(bf16x8*)&Ks[row][c0] = *(const bf16x8*)(k + (size_t)(t*128+row)*HID + head*64 + c0);
    }
    #pragma unroll
    for (int i=0;i<4;i++){
      int s = tid + i*256; int row = s>>3; int c0 = (s&7)*8;
      bf16x8 vv = *(const bf16x8*)(v + (size_t)(t*128+row)*HID + head*64 + c0);
      #pragma unroll
      for (int e=0;e<8;e++) Vt[c0+e][row] = vv[e];
    }
    __syncthreads();

    f32x4 sa[8];
    #pragma unroll
    for (int n=0;n<8;n++) sa[n] = zero4();
    #pragma unroll
    for (int ks=0;ks<2;ks++)
      #pragma unroll
      for (int n=0;n<8;n++){
        bf16x8 kf = *(const bf16x8*)&Ks[n*16 + (lane&15)][ks*32 + (lane>>4)*8];
        sa[n] = __builtin_amdgcn_mfma_f32_16x16x32_bf16(qf[ks], kf, sa[n], 0,0,0);
      }

    float pm[4], rs[4];
    #pragma unroll
    for (int r=0;r<4;r++){
      float mx = sa[0][r];
      #pragma unroll
      for (int n=1;n<8;n++) mx = fmaxf(mx, sa[n][r]);
      pm[r] = mx * 0.125f;
      #pragma unroll
      for (int off=1; off<16; off<<=1) pm[r] = fmaxf(pm[r], __shfl_xor(pm[r], off));
      float mnew  = fmaxf(mrow[r], pm[r]);
      float alpha = __expf(mrow[r] - mnew);
      mrow[r] = mnew; lrow[r] *= alpha;
      #pragma unroll
      for (int n=0;n<4;n++) o[n][r] *= alpha;
      rs[r] = 0.f;
    }
    #pragma unroll
    for (int n=0;n<8;n++)
      #pragma unroll
      for (int r=0;r<4;r++){
        float p = __expf(sa[n][r]*0.125f - mrow[r]);
        rs[r] += p;
        Ps[wave][(lane>>4)*4 + r][n*16 + (lane&15)] = (bf16_t)p;
      }
    #pragma unroll
    for (int r=0;r<4;r++){
      #pragma unroll
      for (int off=1; off<16; off<<=1) rs[r] += __shfl_xor(rs[r], off);
      lrow[r] += rs[r];
    }

    #pragma unroll
    for (int ksv=0;ksv<4;ksv++){
      bf16x8 pf = *(const bf16x8*)&Ps[wave][lane&15][ksv*32 + (lane>>4)*8];
      #pragma unroll
      for (int n=0;n<4;n++){
        bf16x8 vf = *(const bf16x8*)&Vt[n*16 + (lane&15)][ksv*32 + (lane>>4)*8];
        o[n] = __builtin_amdgcn_mfma_f32_16x16x32_bf16(pf, vf, o[n], 0,0,0);
      }
    }
  }

  #pragma unroll
  for (int n=0;n<4;n++)
    #pragma unroll
    for (int r=0;r<4;r++){
      const int gm = qrow0 + (lane>>4)*4 + r;
      const int gd = head*64 + n*16 + (lane&15);
      ctx[(size_t)gm*HID + swz_col(gm, gd)] = (bf16_t)(o[n][r] / lrow[r]);
    }
}

// ============ LN over 4096: x = p0+p1 + bias + resid ============
__global__ __launch_bounds__(256) void ln_final_kernel(
    const float* __restrict__ p, const float* __restrict__ resid,
    const float* __restrict__ bias,
    const float* __restrict__ g, const float* __restrict__ b,
    float* __restrict__ yf, bf16_t* __restrict__ yb)
{
  __shared__ float red[4];
  const int row = blockIdx.x, tid = threadIdx.x;
  const size_t base = (size_t)row * 4096;
  const size_t ps = (size_t)512*4096;
  float vals[16];
  float s = 0.f;
  #pragma unroll
  for (int i=0;i<16;i++){
    int c = i*256 + tid;
    float t = p[base+c] + p[ps+base+c] + bias[c] + resid[base+c];
    vals[i] = t; s += t;
  }
  #pragma unroll
  for (int off=1; off<64; off<<=1) s += __shfl_xor(s, off);
  if (!(tid&63)) red[tid>>6] = s;
  __syncthreads();
  const float mean = (red[0]+red[1]+red[2]+red[3]) * (1.0f/4096.0f);
  __syncthreads();
  float s2 = 0.f;
  #pragma unroll
  for (int i=0;i<16;i++){ float d = vals[i]-mean; s2 += d*d; }
  #pragma unroll
  for (int off=1; off<64; off<<=1) s2 += __shfl_xor(s2, off);
  if (!(tid&63)) red[tid>>6] = s2;
  __syncthreads();
  const float rstd = rsqrtf((red[0]+red[1]+red[2]+red[3])*(1.0f/4096.0f) + 1e-12f);
  #pragma unroll
  for (int i=0;i<16;i++){
    int c = i*256 + tid;
    float y = (vals[i]-mean)*rstd*g[c] + b[c];
    yf[base+c] = y;
    if (yb) yb[base + swz_col(row, c)] = (bf16_t)y;
  }
}

// ============ embeddings + LN(128) -> bf16 swizzled ============
__global__ __launch_bounds__(128) void embed_ln_kernel(
    const float* __restrict__ we, const float* __restrict__ te, const float* __restrict__ pe,
    const float* __restrict__ g, const float* __restrict__ bb,
    const int* __restrict__ ids, const int* __restrict__ tt, const int* __restrict__ pos,
    bf16_t* __restrict__ out)
{
  __shared__ float red[2];
  const int row = blockIdx.x, tid = threadIdx.x;
  float e = we[(size_t)ids[row]*128 + tid] + te[(size_t)tt[row]*128 + tid] + pe[(size_t)pos[row]*128 + tid];
  float s = e;
  #pragma unroll
  for (int off=1; off<64; off<<=1) s += __shfl_xor(s, off);
  if (!(tid&63)) red[tid>>6] = s;
  __syncthreads();
  const float mean = (red[0]+red[1]) * (1.0f/128.0f);
  __syncthreads();
  float d = e - mean;
  float s2 = d*d;
  #pragma unroll
  for (int off=1; off<64; off<<=1) s2 += __shfl_xor(s2, off);
  if (!(tid&63)) red[tid>>6] = s2;
  __syncthreads();
  const float var = (red[0]+red[1]) * (1.0f/128.0f);
  float y = d * rsqrtf(var + 1e-12f) * g[tid] + bb[tid];
  out[(size_t)row*128 + swz_col(row, tid)] = (bf16_t)y;
}

// ============ launch ============
extern "C" void kernel_launch(void* const* d_in, const int* in_sizes, int n_in,
                              void* d_out, int out_size, void* d_ws, size_t ws_size,
                              hipStream_t stream) {
  const float* we   = (const float*)d_in[0];
  const float* te   = (const float*)d_in[1];
  const float* pe   = (const float*)d_in[2];
  const float* ln0g = (const float*)d_in[3];
  const float* ln0b = (const float*)d_in[4];
  const float* Wp   = (const float*)d_in[5];
  const float* bp   = (const float*)d_in[6];
  const float* Wq   = (const float*)d_in[7];
  const float* bq   = (const float*)d_in[8];
  const float* Wk   = (const float*)d_in[9];
  const float* bk   = (const float*)d_in[10];
  const float* Wv   = (const float*)d_in[11];
  const float* bv   = (const float*)d_in[12];
  const float* Wo   = (const float*)d_in[13];
  const float* bo   = (const float*)d_in[14];
  const float* ln1g = (const float*)d_in[15];
  const float* ln1b = (const float*)d_in[16];
  const float* Wf1  = (const float*)d_in[17];
  const float* bf1  = (const float*)d_in[18];
  const float* Wf2  = (const float*)d_in[19];
  const float* bf2  = (const float*)d_in[20];
  const float* ln2g = (const float*)d_in[21];
  const float* ln2b = (const float*)d_in[22];
  const int* ids = (const int*)d_in[23];
  const int* tt  = (const int*)d_in[24];
  const int* pos = (const int*)d_in[25];
  float* out = (float*)d_out;

  float* ws = (float*)d_ws;
  const size_t M1 = (size_t)1024*1024;
  float* hidden_f32 = ws;                 // 2M floats
  float* part       = ws + 2*M1;          // 2 x 2M floats
  float* h1_f32     = ws + 6*M1;          // 2M floats
  bf16_t* b16 = (bf16_t*)(ws + 8*M1);
  bf16_t* qb     = b16;                   // 2M elems each
  bf16_t* kb     = b16 + 2*M1;
  bf16_t* vb     = b16 + 4*M1;
  bf16_t* ctxb   = b16 + 6*M1;
  bf16_t* hid_b  = b16 + 8*M1;
  bf16_t* h1_b   = b16 + 10*M1;
  bf16_t* he_b   = b16 + 12*M1;           // 64K elems
  bf16_t* gelu_b = b16;                   // reuse q/k/v/ctx region (8M elems)

  // embeddings + LN0 -> h_e bf16 swizzled
  embed_ln_kernel<<<dim3(512),dim3(128),0,stream>>>(we,te,pe,ln0g,ln0b,ids,tt,pos,he_b);
  // hidden = h_e @ Wp^T + bp : fp32 linear + bf16 swz   (256 blocks)
  gemm128_kernel<5><<<dim3(256),dim3(256),0,stream>>>(he_b, Wp, bp, hidden_f32, hid_b, 4096, 128, 64);
  // q,k,v bf16 linear   (768 blocks)
  gemm128_qkv_kernel<<<dim3(768),dim3(256),0,stream>>>(hid_b, Wq,Wk,Wv, bq,bk,bv, qb,kb,vb);
  // attention -> ctx bf16 swizzled   (512 blocks)
  attn_kernel<<<dim3(8,64),dim3(256),0,stream>>>(qb, kb, vb, ctxb);
  // attn_out partials = ctx @ Wo^T, split-K=2   (512 blocks)
  gemm128_kernel<1><<<dim3(512),dim3(256),0,stream>>>(ctxb, Wo, nullptr, part, nullptr, 4096, 4096, 64);
  // h1 = LN(p0+p1 + bo + hidden) -> fp32 + bf16 swz
  ln_final_kernel<<<dim3(512),dim3(256),0,stream>>>(part, hidden_f32, bo, ln1g, ln1b, h1_f32, h1_b);
  // gelu(h1 @ Wf1^T + bf1) -> bf16 swizzled   (1024 blocks)
  gemm128_kernel<12><<<dim3(1024),dim3(256),0,stream>>>(h1_b, Wf1, bf1, nullptr, gelu_b, 16384, 4096, 256);
  // ff2 partials = gelu @ Wf2^T, split-K=2   (512 blocks)
  gemm128_kernel<1><<<dim3(512),dim3(256),0,stream>>>(gelu_b, Wf2, nullptr, part, nullptr, 4096, 16384, 64);
  // out = LN(p0+p1 + bf2 + h1)
  ln_final_kernel<<<dim3(512),dim3(256),0,stream>>>(part, h1_f32, bf2, ln2g, ln2b, out, nullptr);
}

// Round 6
// 665.874 us; speedup vs baseline: 1.0851x; 1.0851x over previous
//
#include <hip/hip_runtime.h>
#include <hip/hip_bf16.h>
#include <cmath>

typedef __bf16 bf16_t;
typedef bf16_t bf16x8 __attribute__((ext_vector_type(8)));
typedef float f32x4 __attribute__((ext_vector_type(4)));

__device__ __forceinline__ f32x4 zero4(){ f32x4 z; z[0]=0.f; z[1]=0.f; z[2]=0.f; z[3]=0.f; return z; }

__device__ __forceinline__ bf16x8 cvt8(float4 a, float4 b){
  bf16x8 r;
  r[0]=(bf16_t)a.x; r[1]=(bf16_t)a.y; r[2]=(bf16_t)a.z; r[3]=(bf16_t)a.w;
  r[4]=(bf16_t)b.x; r[5]=(bf16_t)b.y; r[6]=(bf16_t)b.z; r[7]=(bf16_t)b.w;
  return r;
}

__device__ __forceinline__ float gelu_tanh_f(float x){
  float x3 = x*x*x;
  return 0.5f*x*(1.0f + tanhf(0.7978845608028654f*(x + 0.044715f*x3)));
}

// chunk swizzle for bf16 A-operands: 16B chunk (col>>3)&3 XOR'd by (row>>1)&3
__device__ __forceinline__ int swz_col(int row, int col){
  return (col & ~31) | (((((col>>3)&3) ^ ((row>>1)&3)))<<3) | (col&7);
}

#if defined(__has_builtin)
#if __has_builtin(__builtin_amdgcn_global_load_lds)
#define HAS_GLDS 1
#endif
#endif

__device__ __forceinline__ void async_cp16(const bf16_t* g, bf16_t* l){
#ifdef HAS_GLDS
  __builtin_amdgcn_global_load_lds(
      (const __attribute__((address_space(1))) unsigned int*)g,
      (__attribute__((address_space(3))) unsigned int*)l, 16, 0, 0);
#else
  *(bf16x8*)(l + (threadIdx.x & 63)*8) = *(const bf16x8*)g;
#endif
}

// ============ GEMM tile body: C[128,64] block of C[512,N] = A_bf16swz[512,K] * W_f32[N,K]^T ============
// EPI bits: 1 = store fp32 linear, 2 = store bf16 linear, 4 = store bf16 swizzled, 8 = gelu
template<int EPI>
__device__ __forceinline__ void gemm128_body(
    const bf16_t* __restrict__ A, const float* __restrict__ Wt,
    const float* __restrict__ biast,
    float* __restrict__ Cf, bf16_t* __restrict__ Cb,
    int Nc, int K, int kt0, int ktn, int brow, int ccol0)
{
  __shared__ __align__(16) bf16_t As[2][128*32];   // linear rows of 64B
  __shared__ __align__(16) bf16_t Bs[2][64*40];    // padded rows of 80B

  const int tid  = threadIdx.x;
  const int lane = tid & 63;
  const int wave = tid >> 6;
  const int wr = wave >> 1, wc = wave & 1;

  auto stageA = [&](int buf, int kt){
    const bf16_t* s = A + (size_t)(brow + (tid>>2))*K + kt*32 + (tid&3)*8;
#ifdef HAS_GLDS
    bf16_t* base = &As[buf][wave*512];
    async_cp16(s,               base);
    async_cp16(s + (size_t)64*K, base + 2048);
#else
    *(bf16x8*)&As[buf][tid*8]        = *(const bf16x8*)s;
    *(bf16x8*)&As[buf][2048 + tid*8] = *(const bf16x8*)(s + (size_t)64*K);
#endif
  };

  float4 gb0, gb1;
  auto loadB = [&](int kt){
    const float* p = Wt + (size_t)(tid>>2)*K + kt*32 + (tid&3)*8;
    gb0 = *(const float4*)p; gb1 = *(const float4*)(p+4);
  };
  auto writeB = [&](int buf){
    *(bf16x8*)&Bs[buf][(tid>>2)*40 + (tid&3)*8] = cvt8(gb0, gb1);
  };

  f32x4 acc[4][2];
  #pragma unroll
  for (int m=0;m<4;m++){ acc[m][0]=zero4(); acc[m][1]=zero4(); }

  stageA(0, kt0);
  loadB(kt0);
  writeB(0);
  __syncthreads();

  for (int t=0; t<ktn; ++t){
    const int cur = t & 1;
    if (t+1 < ktn){ stageA(cur^1, kt0+t+1); loadB(kt0+t+1); }
    bf16x8 af[4], bfr[2];
    #pragma unroll
    for (int m=0;m<4;m++){
      const int R = wr*64 + m*16 + (lane&15);
      const int c = (lane>>4) ^ ((R>>1)&3);
      af[m] = *(const bf16x8*)&As[cur][R*32 + c*8];
    }
    #pragma unroll
    for (int n=0;n<2;n++)
      bfr[n] = *(const bf16x8*)&Bs[cur][(wc*32 + n*16 + (lane&15))*40 + (lane>>4)*8];
    #pragma unroll
    for (int m=0;m<4;m++)
      #pragma unroll
      for (int n=0;n<2;n++)
        acc[m][n] = __builtin_amdgcn_mfma_f32_16x16x32_bf16(af[m], bfr[n], acc[m][n], 0,0,0);
    if (t+1 < ktn) writeB(cur^1);
    __syncthreads();
  }

  #pragma unroll
  for (int m=0;m<4;m++){
    #pragma unroll
    for (int n=0;n<2;n++){
      const int col = wc*32 + n*16 + (lane&15);
      const float bv = biast ? biast[col] : 0.f;
      #pragma unroll
      for (int r=0;r<4;r++){
        const int gm = brow + wr*64 + m*16 + (lane>>4)*4 + r;
        float v = acc[m][n][r] + bv;
        if (EPI & 8) v = gelu_tanh_f(v);
        if (EPI & 1) Cf[(size_t)gm*Nc + ccol0 + col] = v;
        if (EPI & 2) Cb[(size_t)gm*Nc + ccol0 + col] = (bf16_t)v;
        if (EPI & 4) Cb[(size_t)gm*Nc + swz_col(gm, ccol0 + col)] = (bf16_t)v;
      }
    }
  }
}

// XCD-grouped decode: the 4 m-blocks sharing one W-tile (same o) get lin values
// congruent mod 8 -> same XCD, dispatched back-to-back -> W-tile hits that XCD's L2.
// lin = r + 8*(m + 4*q), o = r + 8*q.  Requires ocount % 8 == 0.
template<int EPI>
__global__ __launch_bounds__(256,4) void gemm128_kernel(
    const bf16_t* __restrict__ A, const float* __restrict__ W,
    const float* __restrict__ bias,
    float* __restrict__ Cf, bf16_t* __restrict__ Cb, int N, int K, int nt, int nz)
{
  const int lin = blockIdx.x;
  const int r = lin & 7;
  const int t = lin >> 3;
  const int m = t & 3;
  const int o = r + 8*(t>>2);
  const int n_tile = o % nt;
  const int z = o / nt;
  const int ktn = (K>>5) / nz;
  gemm128_body<EPI>(A, W + (size_t)(n_tile*64)*K,
                    bias ? bias + n_tile*64 : nullptr,
                    (EPI&1) ? Cf + (size_t)z*512*N : nullptr, Cb,
                    N, K, z*ktn, ktn, m*128, n_tile*64);
}

__global__ __launch_bounds__(256,4) void gemm128_qkv_kernel(
    const bf16_t* __restrict__ A,
    const float* __restrict__ W0, const float* __restrict__ W1, const float* __restrict__ W2,
    const float* __restrict__ b0, const float* __restrict__ b1, const float* __restrict__ b2,
    bf16_t* __restrict__ C0, bf16_t* __restrict__ C1, bf16_t* __restrict__ C2)
{
  const int lin = blockIdx.x;
  const int r = lin & 7;
  const int t = lin >> 3;
  const int m = t & 3;
  const int o = r + 8*(t>>2);      // [0,192)
  const int which = o >> 6;
  const int lc = (o & 63) * 64;
  const float* W    = (which==0) ? W0 : ((which==1) ? W1 : W2);
  const float* bias = (which==0) ? b0 : ((which==1) ? b1 : b2);
  bf16_t* C         = (which==0) ? C0 : ((which==1) ? C1 : C2);
  gemm128_body<2>(A, W + (size_t)lc*4096, bias + lc, nullptr, C,
                  4096, 4096, 0, 128, m*128, lc);
}

// ============ flash attention: grid (8 qblocks, 64 heads), 256 thr, 16 q-rows/wave ============
__global__ void attn_kernel(
    const bf16_t* __restrict__ q, const bf16_t* __restrict__ k,
    const bf16_t* __restrict__ v, bf16_t* __restrict__ ctx)
{
  constexpr int HID = 4096;
  const int qblk = blockIdx.x, head = blockIdx.y;
  const int tid = threadIdx.x, lane = tid & 63, wave = tid >> 6;

  __shared__ __align__(16) bf16_t Ks[128][72];
  __shared__ __align__(16) bf16_t Vt[64][136];
  __shared__ __align__(16) bf16_t Ps[4][16][136];

  bf16x8 qf[2];
  const int qrow0 = qblk*64 + wave*16;
  #pragma unroll
  for (int ks=0;ks<2;ks++)
    qf[ks] = *(const bf16x8*)(q + (size_t)(qrow0 + (lane&15))*HID + head*64 + ks*32 + (lane>>4)*8);

  f32x4 o[4];
  float mrow[4], lrow[4];
  #pragma unroll
  for (int n=0;n<4;n++) o[n] = zero4();
  #pragma unroll
  for (int r=0;r<4;r++){ mrow[r] = -1e30f; lrow[r] = 0.f; }

  for (int t=0; t<4; ++t){
    __syncthreads();
    #pragma unroll
    for (int i=0;i<4;i++){
      int s = tid + i*256; int row = s>>3; int c0 = (s&7)*8;
      *(bf16x8*)&Ks[row][c0] = *(const bf16x8*)(k + (size_t)(t*128+row)*HID + head*64 + c0);
    }
    #pragma unroll
    for (int i=0;i<4;i++){
      int s = tid + i*256; int row = s>>3; int c0 = (s&7)*8;
      bf16x8 vv = *(const bf16x8*)(v + (size_t)(t*128+row)*HID + head*64 + c0);
      #pragma unroll
      for (int e=0;e<8;e++) Vt[c0+e][row] = vv[e];
    }
    __syncthreads();

    f32x4 sa[8];
    #pragma unroll
    for (int n=0;n<8;n++) sa[n] = zero4();
    #pragma unroll
    for (int ks=0;ks<2;ks++)
      #pragma unroll
      for (int n=0;n<8;n++){
        bf16x8 kf = *(const bf16x8*)&Ks[n*16 + (lane&15)][ks*32 + (lane>>4)*8];
        sa[n] = __builtin_amdgcn_mfma_f32_16x16x32_bf16(qf[ks], kf, sa[n], 0,0,0);
      }

    float pm[4], rs[4];
    #pragma unroll
    for (int r=0;r<4;r++){
      float mx = sa[0][r];
      #pragma unroll
      for (int n=1;n<8;n++) mx = fmaxf(mx, sa[n][r]);
      pm[r] = mx * 0.125f;
      #pragma unroll
      for (int off=1; off<16; off<<=1) pm[r] = fmaxf(pm[r], __shfl_xor(pm[r], off));
      float mnew  = fmaxf(mrow[r], pm[r]);
      float alpha = __expf(mrow[r] - mnew);
      mrow[r] = mnew; lrow[r] *= alpha;
      #pragma unroll
      for (int n=0;n<4;n++) o[n][r] *= alpha;
      rs[r] = 0.f;
    }
    #pragma unroll
    for (int n=0;n<8;n++)
      #pragma unroll
      for (int r=0;r<4;r++){
        float p = __expf(sa[n][r]*0.125f - mrow[r]);
        rs[r] += p;
        Ps[wave][(lane>>4)*4 + r][n*16 + (lane&15)] = (bf16_t)p;
      }
    #pragma unroll
    for (int r=0;r<4;r++){
      #pragma unroll
      for (int off=1; off<16; off<<=1) rs[r] += __shfl_xor(rs[r], off);
      lrow[r] += rs[r];
    }

    #pragma unroll
    for (int ksv=0;ksv<4;ksv++){
      bf16x8 pf = *(const bf16x8*)&Ps[wave][lane&15][ksv*32 + (lane>>4)*8];
      #pragma unroll
      for (int n=0;n<4;n++){
        bf16x8 vf = *(const bf16x8*)&Vt[n*16 + (lane&15)][ksv*32 + (lane>>4)*8];
        o[n] = __builtin_amdgcn_mfma_f32_16x16x32_bf16(pf, vf, o[n], 0,0,0);
      }
    }
  }

  #pragma unroll
  for (int n=0;n<4;n++)
    #pragma unroll
    for (int r=0;r<4;r++){
      const int gm = qrow0 + (lane>>4)*4 + r;
      const int gd = head*64 + n*16 + (lane&15);
      ctx[(size_t)gm*HID + swz_col(gm, gd)] = (bf16_t)(o[n][r] / lrow[r]);
    }
}

// ============ LN over 4096: x = p0+p1+p2+p3 + bias + resid ============
__global__ __launch_bounds__(256) void ln_final_kernel(
    const float* __restrict__ p, const float* __restrict__ resid,
    const float* __restrict__ bias,
    const float* __restrict__ g, const float* __restrict__ b,
    float* __restrict__ yf, bf16_t* __restrict__ yb)
{
  __shared__ float red[4];
  const int row = blockIdx.x, tid = threadIdx.x;
  const size_t base = (size_t)row * 4096;
  const size_t ps = (size_t)512*4096;
  float vals[16];
  float s = 0.f;
  #pragma unroll
  for (int i=0;i<16;i++){
    int c = i*256 + tid;
    float t = p[base+c] + p[ps+base+c] + p[2*ps+base+c] + p[3*ps+base+c]
            + bias[c] + resid[base+c];
    vals[i] = t; s += t;
  }
  #pragma unroll
  for (int off=1; off<64; off<<=1) s += __shfl_xor(s, off);
  if (!(tid&63)) red[tid>>6] = s;
  __syncthreads();
  const float mean = (red[0]+red[1]+red[2]+red[3]) * (1.0f/4096.0f);
  __syncthreads();
  float s2 = 0.f;
  #pragma unroll
  for (int i=0;i<16;i++){ float d = vals[i]-mean; s2 += d*d; }
  #pragma unroll
  for (int off=1; off<64; off<<=1) s2 += __shfl_xor(s2, off);
  if (!(tid&63)) red[tid>>6] = s2;
  __syncthreads();
  const float rstd = rsqrtf((red[0]+red[1]+red[2]+red[3])*(1.0f/4096.0f) + 1e-12f);
  #pragma unroll
  for (int i=0;i<16;i++){
    int c = i*256 + tid;
    float y = (vals[i]-mean)*rstd*g[c] + b[c];
    yf[base+c] = y;
    if (yb) yb[base + swz_col(row, c)] = (bf16_t)y;
  }
}

// ============ embeddings + LN(128) -> bf16 swizzled ============
__global__ __launch_bounds__(128) void embed_ln_kernel(
    const float* __restrict__ we, const float* __restrict__ te, const float* __restrict__ pe,
    const float* __restrict__ g, const float* __restrict__ bb,
    const int* __restrict__ ids, const int* __restrict__ tt, const int* __restrict__ pos,
    bf16_t* __restrict__ out)
{
  __shared__ float red[2];
  const int row = blockIdx.x, tid = threadIdx.x;
  float e = we[(size_t)ids[row]*128 + tid] + te[(size_t)tt[row]*128 + tid] + pe[(size_t)pos[row]*128 + tid];
  float s = e;
  #pragma unroll
  for (int off=1; off<64; off<<=1) s += __shfl_xor(s, off);
  if (!(tid&63)) red[tid>>6] = s;
  __syncthreads();
  const float mean = (red[0]+red[1]) * (1.0f/128.0f);
  __syncthreads();
  float d = e - mean;
  float s2 = d*d;
  #pragma unroll
  for (int off=1; off<64; off<<=1) s2 += __shfl_xor(s2, off);
  if (!(tid&63)) red[tid>>6] = s2;
  __syncthreads();
  const float var = (red[0]+red[1]) * (1.0f/128.0f);
  float y = d * rsqrtf(var + 1e-12f) * g[tid] + bb[tid];
  out[(size_t)row*128 + swz_col(row, tid)] = (bf16_t)y;
}

// ============ launch ============
extern "C" void kernel_launch(void* const* d_in, const int* in_sizes, int n_in,
                              void* d_out, int out_size, void* d_ws, size_t ws_size,
                              hipStream_t stream) {
  const float* we   = (const float*)d_in[0];
  const float* te   = (const float*)d_in[1];
  const float* pe   = (const float*)d_in[2];
  const float* ln0g = (const float*)d_in[3];
  const float* ln0b = (const float*)d_in[4];
  const float* Wp   = (const float*)d_in[5];
  const float* bp   = (const float*)d_in[6];
  const float* Wq   = (const float*)d_in[7];
  const float* bq   = (const float*)d_in[8];
  const float* Wk   = (const float*)d_in[9];
  const float* bk   = (const float*)d_in[10];
  const float* Wv   = (const float*)d_in[11];
  const float* bv   = (const float*)d_in[12];
  const float* Wo   = (const float*)d_in[13];
  const float* bo   = (const float*)d_in[14];
  const float* ln1g = (const float*)d_in[15];
  const float* ln1b = (const float*)d_in[16];
  const float* Wf1  = (const float*)d_in[17];
  const float* bf1  = (const float*)d_in[18];
  const float* Wf2  = (const float*)d_in[19];
  const float* bf2  = (const float*)d_in[20];
  const float* ln2g = (const float*)d_in[21];
  const float* ln2b = (const float*)d_in[22];
  const int* ids = (const int*)d_in[23];
  const int* tt  = (const int*)d_in[24];
  const int* pos = (const int*)d_in[25];
  float* out = (float*)d_out;

  float* ws = (float*)d_ws;
  const size_t M1 = (size_t)1024*1024;
  float* hidden_f32 = ws;                 // 2M floats
  float* part       = ws + 2*M1;          // 4 x 2M floats
  float* h1_f32     = ws + 10*M1;         // 2M floats
  bf16_t* b16 = (bf16_t*)(ws + 12*M1);
  bf16_t* qb     = b16;                   // 2M elems each
  bf16_t* kb     = b16 + 2*M1;
  bf16_t* vb     = b16 + 4*M1;
  bf16_t* ctxb   = b16 + 6*M1;
  bf16_t* hid_b  = b16 + 8*M1;
  bf16_t* h1_b   = b16 + 10*M1;
  bf16_t* he_b   = b16 + 12*M1;           // 64K elems
  bf16_t* gelu_b = b16;                   // reuse q/k/v/ctx region (8M elems)

  // embeddings + LN0 -> h_e bf16 swizzled
  embed_ln_kernel<<<dim3(512),dim3(128),0,stream>>>(we,te,pe,ln0g,ln0b,ids,tt,pos,he_b);
  // hidden = h_e @ Wp^T + bp : fp32 linear + bf16 swz   (256 blocks, nt=64, nz=1)
  gemm128_kernel<5><<<dim3(256),dim3(256),0,stream>>>(he_b, Wp, bp, hidden_f32, hid_b, 4096, 128, 64, 1);
  // q,k,v bf16 linear   (768 blocks)
  gemm128_qkv_kernel<<<dim3(768),dim3(256),0,stream>>>(hid_b, Wq,Wk,Wv, bq,bk,bv, qb,kb,vb);
  // attention -> ctx bf16 swizzled   (512 blocks)
  attn_kernel<<<dim3(8,64),dim3(256),0,stream>>>(qb, kb, vb, ctxb);
  // attn_out partials = ctx @ Wo^T, split-K=4   (1024 blocks, nt=64, nz=4)
  gemm128_kernel<1><<<dim3(1024),dim3(256),0,stream>>>(ctxb, Wo, nullptr, part, nullptr, 4096, 4096, 64, 4);
  // h1 = LN(p0..p3 + bo + hidden) -> fp32 + bf16 swz
  ln_final_kernel<<<dim3(512),dim3(256),0,stream>>>(part, hidden_f32, bo, ln1g, ln1b, h1_f32, h1_b);
  // gelu(h1 @ Wf1^T + bf1) -> bf16 swizzled   (1024 blocks, nt=256, nz=1)
  gemm128_kernel<12><<<dim3(1024),dim3(256),0,stream>>>(h1_b, Wf1, bf1, nullptr, gelu_b, 16384, 4096, 256, 1);
  // ff2 partials = gelu @ Wf2^T, split-K=4   (1024 blocks, nt=64, nz=4)
  gemm128_kernel<1><<<dim3(1024),dim3(256),0,stream>>>(gelu_b, Wf2, nullptr, part, nullptr, 4096, 16384, 64, 4);
  // out = LN(p0..p3 + bf2 + h1)
  ln_final_kernel<<<dim3(512),dim3(256),0,stream>>>(part, h1_f32, bf2, ln2g, ln2b, out, nullptr);
}